// Round 1
// baseline (312.351 us; speedup 1.0000x reference)
//
#include <hip/hip_runtime.h>
#include <math.h>

#define LSEQ 512
#define DMODEL 512
#define DT 64
#define DFF 2048
#define RB 8   // rows per block for front/mid kernels

__device__ __forceinline__ float wave_sum(float v) {
#pragma unroll
  for (int o = 32; o > 0; o >>= 1) v += __shfl_xor(v, o, 64);
  return v;
}

// ---------------- Kernel 1: LN1 + (fc, lin_in) projections + wa projection + a-map ----
__global__ __launch_bounds__(256) void k_front(
    const float* __restrict__ x, const float* __restrict__ g1, const float* __restrict__ be1,
    const float* __restrict__ fcw, const float* __restrict__ fcb,
    const float* __restrict__ liw, const float* __restrict__ lib,
    const float* __restrict__ wa,
    float* __restrict__ y_o, float* __restrict__ u_o,
    float* __restrict__ ar_o, float* __restrict__ ai_o)
{
  __shared__ float xs[RB][DMODEL];
  __shared__ float wt[128][65];
  __shared__ float us[RB][65];
  __shared__ float aus[RB][129];
  const int tid = threadIdx.x;
  const int row0 = blockIdx.x * RB;
  const int lane = tid & 63, wv = tid >> 6;

  // LayerNorm1: each wave handles 2 rows
#pragma unroll
  for (int rr = 0; rr < 2; ++rr) {
    const int r = wv * 2 + rr;
    const float* xr = x + (size_t)(row0 + r) * DMODEL;
    float v[8]; float s = 0.f;
#pragma unroll
    for (int j = 0; j < 8; ++j) { v[j] = xr[lane + 64 * j]; s += v[j]; }
    s = wave_sum(s);
    const float mu = s * (1.f / 512.f);
    float q = 0.f;
#pragma unroll
    for (int j = 0; j < 8; ++j) { float dd = v[j] - mu; q += dd * dd; }
    q = wave_sum(q);
    const float rstd = rsqrtf(q * (1.f / 512.f) + 1e-5f);
#pragma unroll
    for (int j = 0; j < 8; ++j) {
      int idx = lane + 64 * j;
      xs[r][idx] = (v[j] - mu) * rstd * g1[idx] + be1[idx];
    }
  }
  __syncthreads();

  // y = silu(xn@fc_w^T + fc_b), u = xn@lin_in_w^T + lin_in_b
  // 128 "columns": 0..63 -> fc, 64..127 -> lin_in. Each thread: 1 col x 4 rows.
  const int c = tid & 127, rg = tid >> 7;
  float acc[4] = {0.f, 0.f, 0.f, 0.f};
  for (int kt = 0; kt < 8; ++kt) {
#pragma unroll
    for (int j = 0; j < 32; ++j) {
      int lin = j * 256 + tid;
      int cc = lin >> 6, kk = lin & 63;
      wt[cc][kk] = (cc < 64) ? fcw[cc * DMODEL + kt * 64 + kk]
                             : liw[(cc - 64) * DMODEL + kt * 64 + kk];
    }
    __syncthreads();
    for (int kk = 0; kk < 64; ++kk) {
      float w_ = wt[c][kk];
#pragma unroll
      for (int i = 0; i < 4; ++i) acc[i] = fmaf(w_, xs[rg * 4 + i][kt * 64 + kk], acc[i]);
    }
    __syncthreads();
  }
  if (c < DT) {
    float bb = fcb[c];
#pragma unroll
    for (int i = 0; i < 4; ++i) {
      int row = row0 + rg * 4 + i;
      float v = acc[i] + bb;
      y_o[row * DT + c] = v / (1.f + expf(-v));   // silu
    }
  } else {
    int d = c - DT; float bb = lib[d];
#pragma unroll
    for (int i = 0; i < 4; ++i) {
      int r = rg * 4 + i;
      float v = acc[i] + bb;
      u_o[(row0 + r) * DT + d] = v;
      us[r][d] = v;
    }
  }
  __syncthreads();

  // au = u @ wa^T   (wa: (128,64))
#pragma unroll
  for (int j = 0; j < 32; ++j) {
    int lin = j * 256 + tid; int cc = lin >> 6, kk = lin & 63;
    wt[cc][kk] = wa[cc * DT + kk];
  }
  __syncthreads();
  float aacc[4] = {0.f, 0.f, 0.f, 0.f};
  for (int kk = 0; kk < 64; ++kk) {
    float w_ = wt[c][kk];
#pragma unroll
    for (int i = 0; i < 4; ++i) aacc[i] = fmaf(w_, us[rg * 4 + i][kk], aacc[i]);
  }
#pragma unroll
  for (int i = 0; i < 4; ++i) aus[rg * 4 + i][c] = aacc[i];
  __syncthreads();

  // a = (re + i im) * rsqrt(re^2+im^2) * exp(-(re^2+im^2))
  for (int p = tid; p < RB * DT; p += 256) {
    int r = p >> 6, d = p & 63;
    float re = aus[r][2 * d], im = aus[r][2 * d + 1];
    float asq = re * re + im * im;
    float sc = rsqrtf(asq) * expf(-asq);
    int row = row0 + r;
    ar_o[row * DT + d] = re * sc;
    ai_o[row * DT + d] = im * sc;
  }
}

// ---------------- Kernel 2: backward complex scan  h[i] = xin[i-1] + a_i*h[i+1] ------
__global__ void k_scan(const float* __restrict__ u, const float* __restrict__ ar,
                       const float* __restrict__ ai, const float* __restrict__ hr,
                       const float* __restrict__ hi, float* __restrict__ h_o)
{
  const int tid = threadIdx.x;          // 0..127
  const int b = tid >> 6, d = tid & 63;
  const size_t base = (size_t)b * LSEQ * DT + d;
  // r_L = xin[L-1] = u[b][L-2][d]
  float rre = u[base + (size_t)(LSEQ - 2) * DT];
  float rim = 0.f;
#pragma unroll 16
  for (int i = LSEQ - 1; i >= 1; --i) {
    float a_r = ar[base + (size_t)i * DT];
    float a_i = ai[base + (size_t)i * DT];
    float bre, bim;
    if (i >= 2) { bre = u[base + (size_t)(i - 2) * DT]; bim = 0.f; }
    else        { bre = hr[d];                          bim = hi[d]; }
    float nre = fmaf(a_r, rre, fmaf(-a_i, rim, bre));
    float nim = fmaf(a_r, rim, fmaf( a_i, rre, bim));
    rre = nre; rim = nim;
    float outv = rre;
    if (i == LSEQ - 1) outv += u[base + (size_t)(LSEQ - 1) * DT];  // final .add
    h_o[base + (size_t)i * DT] = outv;
  }
  float a_r = ar[base], a_i = ai[base];
  h_o[base] = a_r * rre - a_i * rim;    // h[0] = a_0 * h[1]
}

// ---------------- Kernel 3: (h*y)@lin_out^T + b + x_res -> x2 ; LN2 -> xn2 -----------
__global__ __launch_bounds__(256) void k_mid(
    const float* __restrict__ h, const float* __restrict__ y,
    const float* __restrict__ low, const float* __restrict__ lob,
    const float* __restrict__ x, const float* __restrict__ g2, const float* __restrict__ be2,
    float* __restrict__ x2_o, float* __restrict__ xn2_o)
{
  __shared__ float hy[RB][65];
  __shared__ float wt[128][65];
  __shared__ float x2s[RB][DMODEL];
  const int tid = threadIdx.x;
  const int row0 = blockIdx.x * RB;
  for (int p = tid; p < RB * DT; p += 256) {
    int r = p >> 6, dd = p & 63;
    int row = row0 + r;
    hy[r][dd] = h[row * DT + dd] * y[row * DT + dd];
  }
  __syncthreads();
  const int c = tid & 127, rg = tid >> 7;
  for (int ot = 0; ot < 4; ++ot) {
#pragma unroll
    for (int j = 0; j < 32; ++j) {
      int lin = j * 256 + tid; int cc = lin >> 6, kk = lin & 63;
      wt[cc][kk] = low[(ot * 128 + cc) * DT + kk];
    }
    __syncthreads();
    float acc[4] = {0.f, 0.f, 0.f, 0.f};
    for (int kk = 0; kk < 64; ++kk) {
      float w_ = wt[c][kk];
#pragma unroll
      for (int i = 0; i < 4; ++i) acc[i] = fmaf(w_, hy[rg * 4 + i][kk], acc[i]);
    }
    int o = ot * 128 + c;
#pragma unroll
    for (int i = 0; i < 4; ++i) {
      int r = rg * 4 + i, row = row0 + r;
      float v = acc[i] + lob[o] + x[(size_t)row * DMODEL + o];
      x2s[r][o] = v;
      x2_o[(size_t)row * DMODEL + o] = v;
    }
    __syncthreads();
  }
  // LN2
  const int lane = tid & 63, wv = tid >> 6;
#pragma unroll
  for (int rr = 0; rr < 2; ++rr) {
    const int r = wv * 2 + rr;
    float v[8]; float s = 0.f;
#pragma unroll
    for (int j = 0; j < 8; ++j) { v[j] = x2s[r][lane + 64 * j]; s += v[j]; }
    s = wave_sum(s);
    const float mu = s * (1.f / 512.f);
    float q = 0.f;
#pragma unroll
    for (int j = 0; j < 8; ++j) { float dd = v[j] - mu; q += dd * dd; }
    q = wave_sum(q);
    const float rstd = rsqrtf(q * (1.f / 512.f) + 1e-5f);
    const int row = row0 + r;
#pragma unroll
    for (int j = 0; j < 8; ++j) {
      int idx = lane + 64 * j;
      xn2_o[(size_t)row * DMODEL + idx] = (v[j] - mu) * rstd * g2[idx] + be2[idx];
    }
  }
}

// ---------------- FFN GEMMs (fp32, 64x64 tile, 4x4 per thread) -----------------------
#define BM 64
#define BN 64
#define BK 32

__global__ __launch_bounds__(256) void k_gemm_silu(
    const float* __restrict__ A,   // (1024, 512)  xn2
    const float* __restrict__ W,   // (2048, 512)  w1
    const float* __restrict__ bs,  // (2048)
    float* __restrict__ C)         // (1024, 2048) h1
{
  __shared__ __align__(16) float As[BK][BM + 4];
  __shared__ __align__(16) float Bs[BK][BN + 4];
  const int tid = threadIdx.x;
  const int m0 = blockIdx.x * BM, n0 = blockIdx.y * BN;
  const int tm = tid & 15, tn = tid >> 4;
  float acc[4][4] = {};
  for (int k0 = 0; k0 < DMODEL; k0 += BK) {
#pragma unroll
    for (int j = 0; j < 8; ++j) {
      int lin = j * 256 + tid;
      int m = lin >> 5, kk = lin & 31;
      As[kk][m] = A[(size_t)(m0 + m) * DMODEL + k0 + kk];
      Bs[kk][m] = W[(size_t)(n0 + m) * DMODEL + k0 + kk];
    }
    __syncthreads();
#pragma unroll
    for (int kk = 0; kk < BK; ++kk) {
      float4 av = *(const float4*)&As[kk][tm * 4];
      float4 bv = *(const float4*)&Bs[kk][tn * 4];
      float a[4] = {av.x, av.y, av.z, av.w};
      float b[4] = {bv.x, bv.y, bv.z, bv.w};
#pragma unroll
      for (int i = 0; i < 4; ++i)
#pragma unroll
        for (int j = 0; j < 4; ++j) acc[i][j] = fmaf(a[i], b[j], acc[i][j]);
    }
    __syncthreads();
  }
#pragma unroll
  for (int i = 0; i < 4; ++i)
#pragma unroll
    for (int j = 0; j < 4; ++j) {
      int r = m0 + tm * 4 + i, f = n0 + tn * 4 + j;
      float v = acc[i][j] + bs[f];
      C[(size_t)r * DFF + f] = v / (1.f + expf(-v));   // silu
    }
}

__global__ __launch_bounds__(256) void k_gemm_out(
    const float* __restrict__ A,   // (1024, 2048) h1
    const float* __restrict__ W,   // (512, 2048)  w2
    const float* __restrict__ bs,  // (512)
    const float* __restrict__ res, // (1024, 512)  x2
    float* __restrict__ C)         // (1024, 512)  out
{
  __shared__ __align__(16) float As[BK][BM + 4];
  __shared__ __align__(16) float Bs[BK][BN + 4];
  const int tid = threadIdx.x;
  const int m0 = blockIdx.x * BM, n0 = blockIdx.y * BN;
  const int tm = tid & 15, tn = tid >> 4;
  float acc[4][4] = {};
  for (int k0 = 0; k0 < DFF; k0 += BK) {
#pragma unroll
    for (int j = 0; j < 8; ++j) {
      int lin = j * 256 + tid;
      int m = lin >> 5, kk = lin & 31;
      As[kk][m] = A[(size_t)(m0 + m) * DFF + k0 + kk];
      Bs[kk][m] = W[(size_t)(n0 + m) * DFF + k0 + kk];
    }
    __syncthreads();
#pragma unroll
    for (int kk = 0; kk < BK; ++kk) {
      float4 av = *(const float4*)&As[kk][tm * 4];
      float4 bv = *(const float4*)&Bs[kk][tn * 4];
      float a[4] = {av.x, av.y, av.z, av.w};
      float b[4] = {bv.x, bv.y, bv.z, bv.w};
#pragma unroll
      for (int i = 0; i < 4; ++i)
#pragma unroll
        for (int j = 0; j < 4; ++j) acc[i][j] = fmaf(a[i], b[j], acc[i][j]);
    }
    __syncthreads();
  }
#pragma unroll
  for (int i = 0; i < 4; ++i)
#pragma unroll
    for (int j = 0; j < 4; ++j) {
      int r = m0 + tm * 4 + i, o = n0 + tn * 4 + j;
      float v = acc[i][j] + bs[o] + res[(size_t)r * DMODEL + o];
      C[(size_t)r * DMODEL + o] = v;
    }
}

// ---------------- launch -------------------------------------------------------------
extern "C" void kernel_launch(void* const* d_in, const int* in_sizes, int n_in,
                              void* d_out, int out_size, void* d_ws, size_t ws_size,
                              hipStream_t stream) {
  const float* x    = (const float*)d_in[0];
  const float* ln1g = (const float*)d_in[1];
  const float* ln1b = (const float*)d_in[2];
  const float* fcw  = (const float*)d_in[3];
  const float* fcb  = (const float*)d_in[4];
  const float* liw  = (const float*)d_in[5];
  const float* lib  = (const float*)d_in[6];
  const float* wa   = (const float*)d_in[7];
  const float* hidr = (const float*)d_in[8];
  const float* hidi = (const float*)d_in[9];
  const float* low  = (const float*)d_in[10];
  const float* lob  = (const float*)d_in[11];
  const float* ln2g = (const float*)d_in[12];
  const float* ln2b = (const float*)d_in[13];
  const float* w1   = (const float*)d_in[14];
  const float* b1   = (const float*)d_in[15];
  const float* w2   = (const float*)d_in[16];
  const float* b2   = (const float*)d_in[17];
  float* out = (float*)d_out;
  float* ws  = (float*)d_ws;

  const int R = 2 * LSEQ;           // 1024 rows
  float* y_   = ws;                 // R*DT
  float* u_   = y_   + R * DT;      // R*DT
  float* ar_  = u_   + R * DT;      // R*DT
  float* ai_  = ar_  + R * DT;      // R*DT
  float* h_   = ai_  + R * DT;      // R*DT
  float* x2_  = h_   + R * DT;      // R*DMODEL
  float* xn2_ = x2_  + R * DMODEL;  // R*DMODEL
  float* h1_  = xn2_ + R * DMODEL;  // R*DFF

  k_front<<<R / RB, 256, 0, stream>>>(x, ln1g, ln1b, fcw, fcb, liw, lib, wa,
                                      y_, u_, ar_, ai_);
  k_scan<<<1, 128, 0, stream>>>(u_, ar_, ai_, hidr, hidi, h_);
  k_mid<<<R / RB, 256, 0, stream>>>(h_, y_, low, lob, x, ln2g, ln2b, x2_, xn2_);
  dim3 g1(R / BM, DFF / BN);        // (16, 32)
  k_gemm_silu<<<g1, 256, 0, stream>>>(xn2_, w1, b1, h1_);
  dim3 g2(R / BM, DMODEL / BN);     // (16, 8)
  k_gemm_out<<<g2, 256, 0, stream>>>(h1_, w2, b2, x2_, out);
}

// Round 2
// 103.093 us; speedup vs baseline: 3.0298x; 3.0298x over previous
//
#include <hip/hip_runtime.h>
#include <math.h>

#define LSEQ 512
#define DMODEL 512
#define DT 64
#define DFF 2048
#define RB 8   // rows per block for front/mid kernels

typedef unsigned short u16;
typedef __attribute__((ext_vector_type(8))) short short8;
typedef __attribute__((ext_vector_type(4))) float f32x4;

__device__ __forceinline__ float wave_sum(float v) {
#pragma unroll
  for (int o = 32; o > 0; o >>= 1) v += __shfl_xor(v, o, 64);
  return v;
}

__device__ __forceinline__ u16 f2bf(float f) {
  unsigned int u = __float_as_uint(f);
  u += 0x7fffu + ((u >> 16) & 1u);
  return (u16)(u >> 16);
}

__device__ __forceinline__ void gload_lds16(const void* g, void* l) {
  __builtin_amdgcn_global_load_lds(
      (const __attribute__((address_space(1))) unsigned int*)g,
      (__attribute__((address_space(3))) unsigned int*)l, 16, 0, 0);
}

// ---------------- fp32 -> bf16 conversion (weights) ----------------------------------
__global__ __launch_bounds__(256) void k_cvt(const float* __restrict__ s,
                                             u16* __restrict__ d, int n4) {
  int i = blockIdx.x * 256 + threadIdx.x;
  if (i < n4) {
    float4 v = ((const float4*)s)[i];
    ushort4 o;
    o.x = f2bf(v.x); o.y = f2bf(v.y); o.z = f2bf(v.z); o.w = f2bf(v.w);
    ((ushort4*)d)[i] = o;
  }
}

// ---------------- Kernel 1: LN1 + (fc, lin_in) projections + wa projection + a-map ----
__global__ __launch_bounds__(256) void k_front(
    const float* __restrict__ x, const float* __restrict__ g1, const float* __restrict__ be1,
    const float* __restrict__ fcw, const float* __restrict__ fcb,
    const float* __restrict__ liw, const float* __restrict__ lib,
    const float* __restrict__ wa,
    float* __restrict__ y_o, float* __restrict__ u_o,
    float* __restrict__ ar_o, float* __restrict__ ai_o)
{
  __shared__ float xs[RB][DMODEL];
  __shared__ float wt[128][65];
  __shared__ float us[RB][65];
  __shared__ float aus[RB][129];
  const int tid = threadIdx.x;
  const int row0 = blockIdx.x * RB;
  const int lane = tid & 63, wv = tid >> 6;

#pragma unroll
  for (int rr = 0; rr < 2; ++rr) {
    const int r = wv * 2 + rr;
    const float* xr = x + (size_t)(row0 + r) * DMODEL;
    float v[8]; float s = 0.f;
#pragma unroll
    for (int j = 0; j < 8; ++j) { v[j] = xr[lane + 64 * j]; s += v[j]; }
    s = wave_sum(s);
    const float mu = s * (1.f / 512.f);
    float q = 0.f;
#pragma unroll
    for (int j = 0; j < 8; ++j) { float dd = v[j] - mu; q += dd * dd; }
    q = wave_sum(q);
    const float rstd = rsqrtf(q * (1.f / 512.f) + 1e-5f);
#pragma unroll
    for (int j = 0; j < 8; ++j) {
      int idx = lane + 64 * j;
      xs[r][idx] = (v[j] - mu) * rstd * g1[idx] + be1[idx];
    }
  }
  __syncthreads();

  const int c = tid & 127, rg = tid >> 7;
  float acc[4] = {0.f, 0.f, 0.f, 0.f};
  for (int kt = 0; kt < 8; ++kt) {
#pragma unroll
    for (int j = 0; j < 32; ++j) {
      int lin = j * 256 + tid;
      int cc = lin >> 6, kk = lin & 63;
      wt[cc][kk] = (cc < 64) ? fcw[cc * DMODEL + kt * 64 + kk]
                             : liw[(cc - 64) * DMODEL + kt * 64 + kk];
    }
    __syncthreads();
    for (int kk = 0; kk < 64; ++kk) {
      float w_ = wt[c][kk];
#pragma unroll
      for (int i = 0; i < 4; ++i) acc[i] = fmaf(w_, xs[rg * 4 + i][kt * 64 + kk], acc[i]);
    }
    __syncthreads();
  }
  if (c < DT) {
    float bb = fcb[c];
#pragma unroll
    for (int i = 0; i < 4; ++i) {
      int row = row0 + rg * 4 + i;
      float v = acc[i] + bb;
      y_o[row * DT + c] = v / (1.f + expf(-v));   // silu
    }
  } else {
    int d = c - DT; float bb = lib[d];
#pragma unroll
    for (int i = 0; i < 4; ++i) {
      int r = rg * 4 + i;
      float v = acc[i] + bb;
      u_o[(row0 + r) * DT + d] = v;
      us[r][d] = v;
    }
  }
  __syncthreads();

#pragma unroll
  for (int j = 0; j < 32; ++j) {
    int lin = j * 256 + tid; int cc = lin >> 6, kk = lin & 63;
    wt[cc][kk] = wa[cc * DT + kk];
  }
  __syncthreads();
  float aacc[4] = {0.f, 0.f, 0.f, 0.f};
  for (int kk = 0; kk < 64; ++kk) {
    float w_ = wt[c][kk];
#pragma unroll
    for (int i = 0; i < 4; ++i) aacc[i] = fmaf(w_, us[rg * 4 + i][kk], aacc[i]);
  }
#pragma unroll
  for (int i = 0; i < 4; ++i) aus[rg * 4 + i][c] = aacc[i];
  __syncthreads();

  for (int p = tid; p < RB * DT; p += 256) {
    int r = p >> 6, d = p & 63;
    float re = aus[r][2 * d], im = aus[r][2 * d + 1];
    float asq = re * re + im * im;
    float sc = rsqrtf(asq) * expf(-asq);
    int row = row0 + r;
    ar_o[row * DT + d] = re * sc;
    ai_o[row * DT + d] = im * sc;
  }
}

// ---------------- Kernel 2: parallel backward affine scan ----------------------------
// r_i = b_i + a_i * r_{i+1},  i = 511..0;  r_512 = u[510];  b_i = xin[i-1] (b_0 = 0)
// One wave per (batch, d) chain; lane l owns steps [8l, 8l+7].
__global__ __launch_bounds__(64) void k_scan2(
    const float* __restrict__ u, const float* __restrict__ ar, const float* __restrict__ ai,
    const float* __restrict__ hr, const float* __restrict__ hi, float* __restrict__ h_o)
{
  const int blk = blockIdx.x;             // 0..127
  const int b = blk >> 6, d = blk & 63;
  const int lane = threadIdx.x;           // 0..63
  const size_t base = (size_t)b * LSEQ * DT + d;
  const int i0 = lane * 8;

  float a_r[8], a_i[8], b_r[8], b_i[8];
#pragma unroll
  for (int e = 0; e < 8; ++e) {
    int i = i0 + e;
    a_r[e] = ar[base + (size_t)i * DT];
    a_i[e] = ai[base + (size_t)i * DT];
    if (i >= 2)      { b_r[e] = u[base + (size_t)(i - 2) * DT]; b_i[e] = 0.f; }
    else if (i == 1) { b_r[e] = hr[d]; b_i[e] = hi[d]; }
    else             { b_r[e] = 0.f;   b_i[e] = 0.f; }
  }

  // local compose: T = M_{i0} o M_{i0+1} o ... o M_{i0+7}   (M(x) = a*x + b, complex)
  float Ar = 1.f, Ai = 0.f, Br = 0.f, Bi = 0.f;
#pragma unroll
  for (int e = 0; e < 8; ++e) {
    float nBr = fmaf(Ar, b_r[e], fmaf(-Ai, b_i[e], Br));
    float nBi = fmaf(Ar, b_i[e], fmaf( Ai, b_r[e], Bi));
    float nAr = Ar * a_r[e] - Ai * a_i[e];
    float nAi = Ar * a_i[e] + Ai * a_r[e];
    Ar = nAr; Ai = nAi; Br = nBr; Bi = nBi;
  }

  // Kogge-Stone suffix scan of affine maps: lane l -> M_l o M_{l+1} o ... o M_63
#pragma unroll
  for (int dlt = 1; dlt < 64; dlt <<= 1) {
    float Ar2 = __shfl_down(Ar, dlt, 64);
    float Ai2 = __shfl_down(Ai, dlt, 64);
    float Br2 = __shfl_down(Br, dlt, 64);
    float Bi2 = __shfl_down(Bi, dlt, 64);
    if (lane + dlt < 64) {
      float nAr = Ar * Ar2 - Ai * Ai2;
      float nAi = Ar * Ai2 + Ai * Ar2;
      float nBr = fmaf(Ar, Br2, fmaf(-Ai, Bi2, Br));
      float nBi = fmaf(Ar, Bi2, fmaf( Ai, Br2, Bi));
      Ar = nAr; Ai = nAi; Br = nBr; Bi = nBi;
    }
  }

  // incoming boundary for this lane: S_{lane+1}(r512), identity for lane 63
  float A1r = __shfl_down(Ar, 1, 64), A1i = __shfl_down(Ai, 1, 64);
  float B1r = __shfl_down(Br, 1, 64), B1i = __shfl_down(Bi, 1, 64);
  if (lane == 63) { A1r = 1.f; A1i = 0.f; B1r = 0.f; B1i = 0.f; }
  const float r512 = u[base + (size_t)(LSEQ - 2) * DT];
  float rr = fmaf(A1r, r512, B1r);
  float ri = fmaf(A1i, r512, B1i);

  const float uL = u[base + (size_t)(LSEQ - 1) * DT];
#pragma unroll
  for (int e = 7; e >= 0; --e) {
    int i = i0 + e;
    float nr = fmaf(a_r[e], rr, fmaf(-a_i[e], ri, b_r[e]));
    float ni = fmaf(a_r[e], ri, fmaf( a_i[e], rr, b_i[e]));
    rr = nr; ri = ni;
    float outv = rr;
    if (i == LSEQ - 1) outv += uL;
    h_o[base + (size_t)i * DT] = outv;
  }
}

// ---------------- Kernel 3: (h*y)@lin_out^T + b + x_res -> x2 ; LN2 -> bf16 xn2 ------
__global__ __launch_bounds__(256) void k_mid(
    const float* __restrict__ h, const float* __restrict__ y,
    const float* __restrict__ low, const float* __restrict__ lob,
    const float* __restrict__ x, const float* __restrict__ g2, const float* __restrict__ be2,
    float* __restrict__ x2_o, u16* __restrict__ xn2b)
{
  __shared__ float hy[RB][65];
  __shared__ float wt[128][65];
  __shared__ float x2s[RB][DMODEL];
  const int tid = threadIdx.x;
  const int row0 = blockIdx.x * RB;
  for (int p = tid; p < RB * DT; p += 256) {
    int r = p >> 6, dd = p & 63;
    int row = row0 + r;
    hy[r][dd] = h[row * DT + dd] * y[row * DT + dd];
  }
  __syncthreads();
  const int c = tid & 127, rg = tid >> 7;
  for (int ot = 0; ot < 4; ++ot) {
#pragma unroll
    for (int j = 0; j < 32; ++j) {
      int lin = j * 256 + tid; int cc = lin >> 6, kk = lin & 63;
      wt[cc][kk] = low[(ot * 128 + cc) * DT + kk];
    }
    __syncthreads();
    float acc[4] = {0.f, 0.f, 0.f, 0.f};
    for (int kk = 0; kk < 64; ++kk) {
      float w_ = wt[c][kk];
#pragma unroll
      for (int i = 0; i < 4; ++i) acc[i] = fmaf(w_, hy[rg * 4 + i][kk], acc[i]);
    }
    int o = ot * 128 + c;
#pragma unroll
    for (int i = 0; i < 4; ++i) {
      int r = rg * 4 + i, row = row0 + r;
      float v = acc[i] + lob[o] + x[(size_t)row * DMODEL + o];
      x2s[r][o] = v;
      x2_o[(size_t)row * DMODEL + o] = v;
    }
    __syncthreads();
  }
  const int lane = tid & 63, wv = tid >> 6;
#pragma unroll
  for (int rr = 0; rr < 2; ++rr) {
    const int r = wv * 2 + rr;
    float v[8]; float s = 0.f;
#pragma unroll
    for (int j = 0; j < 8; ++j) { v[j] = x2s[r][lane + 64 * j]; s += v[j]; }
    s = wave_sum(s);
    const float mu = s * (1.f / 512.f);
    float q = 0.f;
#pragma unroll
    for (int j = 0; j < 8; ++j) { float dd = v[j] - mu; q += dd * dd; }
    q = wave_sum(q);
    const float rstd = rsqrtf(q * (1.f / 512.f) + 1e-5f);
    const int row = row0 + r;
#pragma unroll
    for (int j = 0; j < 8; ++j) {
      int idx = lane + 64 * j;
      xn2b[(size_t)row * DMODEL + idx] = f2bf((v[j] - mu) * rstd * g2[idx] + be2[idx]);
    }
  }
}

// ---------------- bf16 MFMA GEMM:  C(M,N) = A(M,K) @ B(N,K)^T  -----------------------
// EPI=0: v = acc + bias; silu; write bf16 to Cb.   EPI=1: v = acc + bias + res; fp32 Cf.
template<int BM, int BN, int EPI>
__global__ __launch_bounds__(256) void k_mfma(
    const u16* __restrict__ A, const u16* __restrict__ B,
    const float* __restrict__ bias, const float* __restrict__ res,
    float* __restrict__ Cf, u16* __restrict__ Cb, int K, int N)
{
  constexpr int MF = BM / 32, NF = BN / 32;
  __shared__ __align__(16) u16 As[BM * 64];
  __shared__ __align__(16) u16 Bs[BN * 64];
  const int t = threadIdx.x;
  const int m0 = blockIdx.x * BM, n0 = blockIdx.y * BN;
  const int w = t >> 6, lane = t & 63;
  const int wm = w >> 1, wn = w & 1;
  const int lr = lane & 15, lk = lane >> 4;
  f32x4 acc[MF][NF] = {};

  for (int k0 = 0; k0 < K; k0 += 64) {
#pragma unroll
    for (int i = 0; i < BM / 32; ++i) {
      int e = i * 2048 + t * 8;
      int row = e >> 6, col = e & 63;
      gload_lds16(A + (size_t)(m0 + row) * K + k0 + col, &As[e]);
    }
#pragma unroll
    for (int i = 0; i < BN / 32; ++i) {
      int e = i * 2048 + t * 8;
      int row = e >> 6, col = e & 63;
      gload_lds16(B + (size_t)(n0 + row) * K + k0 + col, &Bs[e]);
    }
    __syncthreads();   // compiler drains vmcnt before s_barrier -> LDS ready
#pragma unroll
    for (int ks = 0; ks < 2; ++ks) {
      short8 af[MF], bf[NF];
#pragma unroll
      for (int mf = 0; mf < MF; ++mf)
        af[mf] = *(const short8*)&As[(wm * (BM / 2) + mf * 16 + lr) * 64 + ks * 32 + lk * 8];
#pragma unroll
      for (int nf = 0; nf < NF; ++nf)
        bf[nf] = *(const short8*)&Bs[(wn * (BN / 2) + nf * 16 + lr) * 64 + ks * 32 + lk * 8];
#pragma unroll
      for (int mf = 0; mf < MF; ++mf)
#pragma unroll
        for (int nf = 0; nf < NF; ++nf)
          acc[mf][nf] = __builtin_amdgcn_mfma_f32_16x16x32_bf16(af[mf], bf[nf], acc[mf][nf], 0, 0, 0);
    }
    __syncthreads();
  }

#pragma unroll
  for (int mf = 0; mf < MF; ++mf)
#pragma unroll
    for (int nf = 0; nf < NF; ++nf)
#pragma unroll
      for (int j = 0; j < 4; ++j) {
        int rrow = m0 + wm * (BM / 2) + mf * 16 + lk * 4 + j;
        int ccol = n0 + wn * (BN / 2) + nf * 16 + lr;
        float v = acc[mf][nf][j] + bias[ccol];
        if constexpr (EPI == 0) {
          v = v / (1.f + expf(-v));                       // silu
          Cb[(size_t)rrow * N + ccol] = f2bf(v);
        } else {
          Cf[(size_t)rrow * N + ccol] = v + res[(size_t)rrow * N + ccol];
        }
      }
}

// ---------------- launch -------------------------------------------------------------
extern "C" void kernel_launch(void* const* d_in, const int* in_sizes, int n_in,
                              void* d_out, int out_size, void* d_ws, size_t ws_size,
                              hipStream_t stream) {
  const float* x    = (const float*)d_in[0];
  const float* ln1g = (const float*)d_in[1];
  const float* ln1b = (const float*)d_in[2];
  const float* fcw  = (const float*)d_in[3];
  const float* fcb  = (const float*)d_in[4];
  const float* liw  = (const float*)d_in[5];
  const float* lib  = (const float*)d_in[6];
  const float* wa   = (const float*)d_in[7];
  const float* hidr = (const float*)d_in[8];
  const float* hidi = (const float*)d_in[9];
  const float* low  = (const float*)d_in[10];
  const float* lob  = (const float*)d_in[11];
  const float* ln2g = (const float*)d_in[12];
  const float* ln2b = (const float*)d_in[13];
  const float* w1   = (const float*)d_in[14];
  const float* b1   = (const float*)d_in[15];
  const float* w2   = (const float*)d_in[16];
  const float* b2   = (const float*)d_in[17];
  float* out = (float*)d_out;
  float* ws  = (float*)d_ws;

  const int R = 2 * LSEQ;                      // 1024 rows
  float* y_   = ws;                            // 65536
  float* u_   = y_  + (size_t)R * DT;
  float* ar_  = u_  + (size_t)R * DT;
  float* ai_  = ar_ + (size_t)R * DT;
  float* h_   = ai_ + (size_t)R * DT;
  float* x2_  = h_  + (size_t)R * DT;          // 524288 floats
  u16*  xn2b = (u16*)(x2_ + (size_t)R * DMODEL);   // 524288 u16
  u16*  h1b  = xn2b + (size_t)R * DFF / 2 * 0 + (size_t)R * DMODEL;  // 524288 u16 later
  // (explicit layout)
  h1b        = xn2b + (size_t)R * DMODEL;      // 2097152 u16
  u16*  w1b  = h1b  + (size_t)R * DFF;         // 1048576 u16
  u16*  w2b  = w1b  + (size_t)DFF * DMODEL;    // 1048576 u16

  k_cvt<<<1024, 256, 0, stream>>>(w1, w1b, (DFF * DMODEL) / 4);
  k_cvt<<<1024, 256, 0, stream>>>(w2, w2b, (DFF * DMODEL) / 4);
  k_front<<<R / RB, 256, 0, stream>>>(x, ln1g, ln1b, fcw, fcb, liw, lib, wa,
                                      y_, u_, ar_, ai_);
  k_scan2<<<128, 64, 0, stream>>>(u_, ar_, ai_, hidr, hidi, h_);
  k_mid<<<R / RB, 256, 0, stream>>>(h_, y_, low, lob, x, ln2g, ln2b, x2_, xn2b);
  dim3 g1(R / 128, DFF / 128);                 // (8, 16)
  k_mfma<128, 128, 0><<<g1, 256, 0, stream>>>(xn2b, w1b, b1, nullptr, nullptr, h1b,
                                              DMODEL, DFF);
  dim3 g2(R / 64, DMODEL / 64);                // (16, 8)
  k_mfma<64, 64, 1><<<g2, 256, 0, stream>>>(h1b, w2b, b2, x2_, out, nullptr,
                                            DFF, DMODEL);
}

// Round 5
// 101.299 us; speedup vs baseline: 3.0835x; 1.0177x over previous
//
#include <hip/hip_runtime.h>
#include <math.h>

#define LSEQ 512
#define DMODEL 512
#define DT 64
#define DFF 2048
#define RBF 4   // rows per block for front/mid kernels (256 blocks)

typedef unsigned short u16;
typedef __attribute__((ext_vector_type(8))) short short8;
typedef __attribute__((ext_vector_type(4))) float f32x4;

__device__ __forceinline__ float wave_sum(float v) {
#pragma unroll
  for (int o = 32; o > 0; o >>= 1) v += __shfl_xor(v, o, 64);
  return v;
}

__device__ __forceinline__ u16 f2bf(float f) {
  unsigned int u = __float_as_uint(f);
  u += 0x7fffu + ((u >> 16) & 1u);
  return (u16)(u >> 16);
}

__device__ __forceinline__ void gload_lds16(const void* g, void* l) {
  __builtin_amdgcn_global_load_lds(
      (const __attribute__((address_space(1))) unsigned int*)g,
      (__attribute__((address_space(3))) unsigned int*)l, 16, 0, 0);
}

// ---------------- fp32 -> bf16 conversion: w1 then w2 into one contiguous dst --------
__global__ __launch_bounds__(256) void k_cvt2(const float* __restrict__ s1,
                                              const float* __restrict__ s2,
                                              u16* __restrict__ d, int n4each) {
  int i = blockIdx.x * 256 + threadIdx.x;
  float4 v;
  if (i < n4each)            v = ((const float4*)s1)[i];
  else if (i < 2 * n4each)   v = ((const float4*)s2)[i - n4each];
  else return;
  ushort4 o;
  o.x = f2bf(v.x); o.y = f2bf(v.y); o.z = f2bf(v.z); o.w = f2bf(v.w);
  ((ushort4*)d)[i] = o;
}

// ---------------- Kernel 1: LN1 + (fc, lin_in) projections + wa projection + a-map ----
__global__ __launch_bounds__(256) void k_front(
    const float* __restrict__ x, const float* __restrict__ g1, const float* __restrict__ be1,
    const float* __restrict__ fcw, const float* __restrict__ fcb,
    const float* __restrict__ liw, const float* __restrict__ lib,
    const float* __restrict__ wa,
    float* __restrict__ y_o, float* __restrict__ u_o,
    float* __restrict__ ar_o, float* __restrict__ ai_o)
{
  __shared__ float xs[RBF][DMODEL];
  __shared__ float wt[128][65];
  __shared__ float us[RBF][68];
  __shared__ float aus[RBF][129];
  const int tid = threadIdx.x;
  const int row0 = blockIdx.x * RBF;
  const int lane = tid & 63, wv = tid >> 6;

  // LayerNorm1: wave wv handles row wv
  {
    const int r = wv;
    const float* xr = x + (size_t)(row0 + r) * DMODEL;
    float v[8]; float s = 0.f;
#pragma unroll
    for (int j = 0; j < 8; ++j) { v[j] = xr[lane + 64 * j]; s += v[j]; }
    s = wave_sum(s);
    const float mu = s * (1.f / 512.f);
    float q = 0.f;
#pragma unroll
    for (int j = 0; j < 8; ++j) { float dd = v[j] - mu; q += dd * dd; }
    q = wave_sum(q);
    const float rstd = rsqrtf(q * (1.f / 512.f) + 1e-5f);
#pragma unroll
    for (int j = 0; j < 8; ++j) {
      int idx = lane + 64 * j;
      xs[r][idx] = (v[j] - mu) * rstd * g1[idx] + be1[idx];
    }
  }
  __syncthreads();

  // y = silu(xn@fc_w^T + b), u = xn@lin_in_w^T + b. 128 cols x 2 row-groups.
  const int c = tid & 127, rg = tid >> 7;
  float acc[2] = {0.f, 0.f};
  for (int kt = 0; kt < 8; ++kt) {
#pragma unroll
    for (int j = 0; j < 32; ++j) {
      int lin = j * 256 + tid;
      int cc = lin >> 6, kk = lin & 63;
      wt[cc][kk] = (cc < 64) ? fcw[cc * DMODEL + kt * 64 + kk]
                             : liw[(cc - 64) * DMODEL + kt * 64 + kk];
    }
    __syncthreads();
    for (int k4 = 0; k4 < 64; k4 += 4) {
      float4 xv0 = *(const float4*)&xs[rg * 2 + 0][kt * 64 + k4];
      float4 xv1 = *(const float4*)&xs[rg * 2 + 1][kt * 64 + k4];
      float a0[4] = {xv0.x, xv0.y, xv0.z, xv0.w};
      float a1[4] = {xv1.x, xv1.y, xv1.z, xv1.w};
#pragma unroll
      for (int e = 0; e < 4; ++e) {
        float w_ = wt[c][k4 + e];
        acc[0] = fmaf(w_, a0[e], acc[0]);
        acc[1] = fmaf(w_, a1[e], acc[1]);
      }
    }
    __syncthreads();
  }
  if (c < DT) {
    float bb = fcb[c];
#pragma unroll
    for (int i = 0; i < 2; ++i) {
      int row = row0 + rg * 2 + i;
      float v = acc[i] + bb;
      y_o[row * DT + c] = v / (1.f + expf(-v));   // silu
    }
  } else {
    int d = c - DT; float bb = lib[d];
#pragma unroll
    for (int i = 0; i < 2; ++i) {
      int r = rg * 2 + i;
      float v = acc[i] + bb;
      u_o[(row0 + r) * DT + d] = v;
      us[r][d] = v;
    }
  }
  __syncthreads();

  // au = u @ wa^T   (wa: (128,64))
#pragma unroll
  for (int j = 0; j < 32; ++j) {
    int lin = j * 256 + tid; int cc = lin >> 6, kk = lin & 63;
    wt[cc][kk] = wa[cc * DT + kk];
  }
  __syncthreads();
  float aacc[2] = {0.f, 0.f};
  for (int k4 = 0; k4 < 64; k4 += 4) {
    float4 uv0 = *(const float4*)&us[rg * 2 + 0][k4];
    float4 uv1 = *(const float4*)&us[rg * 2 + 1][k4];
    float a0[4] = {uv0.x, uv0.y, uv0.z, uv0.w};
    float a1[4] = {uv1.x, uv1.y, uv1.z, uv1.w};
#pragma unroll
    for (int e = 0; e < 4; ++e) {
      float w_ = wt[c][k4 + e];
      aacc[0] = fmaf(w_, a0[e], aacc[0]);
      aacc[1] = fmaf(w_, a1[e], aacc[1]);
    }
  }
#pragma unroll
  for (int i = 0; i < 2; ++i) aus[rg * 2 + i][c] = aacc[i];
  __syncthreads();

  // a = (re + i im) * rsqrt(|z|^2) * exp(-|z|^2)
  {
    int r = tid >> 6, d = tid & 63;
    float re = aus[r][2 * d], im = aus[r][2 * d + 1];
    float asq = re * re + im * im;
    float sc = rsqrtf(asq) * expf(-asq);
    int row = row0 + r;
    ar_o[row * DT + d] = re * sc;
    ai_o[row * DT + d] = im * sc;
  }
}

// ---------------- Kernel 2: parallel backward affine scan ----------------------------
__global__ __launch_bounds__(64) void k_scan2(
    const float* __restrict__ u, const float* __restrict__ ar, const float* __restrict__ ai,
    const float* __restrict__ hr, const float* __restrict__ hi, float* __restrict__ h_o)
{
  const int blk = blockIdx.x;             // 0..127
  const int b = blk >> 6, d = blk & 63;
  const int lane = threadIdx.x;           // 0..63
  const size_t base = (size_t)b * LSEQ * DT + d;
  const int i0 = lane * 8;

  float a_r[8], a_i[8], b_r[8], b_i[8];
#pragma unroll
  for (int e = 0; e < 8; ++e) {
    int i = i0 + e;
    a_r[e] = ar[base + (size_t)i * DT];
    a_i[e] = ai[base + (size_t)i * DT];
    if (i >= 2)      { b_r[e] = u[base + (size_t)(i - 2) * DT]; b_i[e] = 0.f; }
    else if (i == 1) { b_r[e] = hr[d]; b_i[e] = hi[d]; }
    else             { b_r[e] = 0.f;   b_i[e] = 0.f; }
  }

  float Ar = 1.f, Ai = 0.f, Br = 0.f, Bi = 0.f;
#pragma unroll
  for (int e = 0; e < 8; ++e) {
    float nBr = fmaf(Ar, b_r[e], fmaf(-Ai, b_i[e], Br));
    float nBi = fmaf(Ar, b_i[e], fmaf( Ai, b_r[e], Bi));
    float nAr = Ar * a_r[e] - Ai * a_i[e];
    float nAi = Ar * a_i[e] + Ai * a_r[e];
    Ar = nAr; Ai = nAi; Br = nBr; Bi = nBi;
  }

#pragma unroll
  for (int dlt = 1; dlt < 64; dlt <<= 1) {
    float Ar2 = __shfl_down(Ar, dlt, 64);
    float Ai2 = __shfl_down(Ai, dlt, 64);
    float Br2 = __shfl_down(Br, dlt, 64);
    float Bi2 = __shfl_down(Bi, dlt, 64);
    if (lane + dlt < 64) {
      float nAr = Ar * Ar2 - Ai * Ai2;
      float nAi = Ar * Ai2 + Ai * Ar2;
      float nBr = fmaf(Ar, Br2, fmaf(-Ai, Bi2, Br));
      float nBi = fmaf(Ar, Bi2, fmaf( Ai, Br2, Bi));
      Ar = nAr; Ai = nAi; Br = nBr; Bi = nBi;
    }
  }

  float A1r = __shfl_down(Ar, 1, 64), A1i = __shfl_down(Ai, 1, 64);
  float B1r = __shfl_down(Br, 1, 64), B1i = __shfl_down(Bi, 1, 64);
  if (lane == 63) { A1r = 1.f; A1i = 0.f; B1r = 0.f; B1i = 0.f; }
  const float r512 = u[base + (size_t)(LSEQ - 2) * DT];
  float rr = fmaf(A1r, r512, B1r);
  float ri = fmaf(A1i, r512, B1i);

  const float uL = u[base + (size_t)(LSEQ - 1) * DT];
#pragma unroll
  for (int e = 7; e >= 0; --e) {
    int i = i0 + e;
    float nr = fmaf(a_r[e], rr, fmaf(-a_i[e], ri, b_r[e]));
    float ni = fmaf(a_r[e], ri, fmaf( a_i[e], rr, b_i[e]));
    rr = nr; ri = ni;
    float outv = rr;
    if (i == LSEQ - 1) outv += uL;
    h_o[base + (size_t)i * DT] = outv;
  }
}

// ---------------- Kernel 3: (h*y)@lin_out^T + b + x_res -> x2 ; LN2 -> bf16 xn2 ------
__global__ __launch_bounds__(256) void k_mid(
    const float* __restrict__ h, const float* __restrict__ y,
    const float* __restrict__ low, const float* __restrict__ lob,
    const float* __restrict__ x, const float* __restrict__ g2, const float* __restrict__ be2,
    float* __restrict__ x2_o, u16* __restrict__ xn2b)
{
  __shared__ float hy[RBF][68];
  __shared__ float wt[128][65];
  __shared__ float x2s[RBF][DMODEL];
  const int tid = threadIdx.x;
  const int row0 = blockIdx.x * RBF;
  {
    int r = tid >> 6, dd = tid & 63;
    int row = row0 + r;
    hy[r][dd] = h[row * DT + dd] * y[row * DT + dd];
  }
  __syncthreads();
  const int c = tid & 127, rg = tid >> 7;
  for (int ot = 0; ot < 4; ++ot) {
#pragma unroll
    for (int j = 0; j < 32; ++j) {
      int lin = j * 256 + tid; int cc = lin >> 6, kk = lin & 63;
      wt[cc][kk] = low[(ot * 128 + cc) * DT + kk];
    }
    __syncthreads();
    float acc[2] = {0.f, 0.f};
    for (int k4 = 0; k4 < 64; k4 += 4) {
      float4 hv0 = *(const float4*)&hy[rg * 2 + 0][k4];
      float4 hv1 = *(const float4*)&hy[rg * 2 + 1][k4];
      float a0[4] = {hv0.x, hv0.y, hv0.z, hv0.w};
      float a1[4] = {hv1.x, hv1.y, hv1.z, hv1.w};
#pragma unroll
      for (int e = 0; e < 4; ++e) {
        float w_ = wt[c][k4 + e];
        acc[0] = fmaf(w_, a0[e], acc[0]);
        acc[1] = fmaf(w_, a1[e], acc[1]);
      }
    }
    int o = ot * 128 + c;
#pragma unroll
    for (int i = 0; i < 2; ++i) {
      int r = rg * 2 + i, row = row0 + r;
      float v = acc[i] + lob[o] + x[(size_t)row * DMODEL + o];
      x2s[r][o] = v;
      x2_o[(size_t)row * DMODEL + o] = v;
    }
    __syncthreads();
  }
  const int lane = tid & 63, wv = tid >> 6;
  {
    const int r = wv;
    float v[8]; float s = 0.f;
#pragma unroll
    for (int j = 0; j < 8; ++j) { v[j] = x2s[r][lane + 64 * j]; s += v[j]; }
    s = wave_sum(s);
    const float mu = s * (1.f / 512.f);
    float q = 0.f;
#pragma unroll
    for (int j = 0; j < 8; ++j) { float dd = v[j] - mu; q += dd * dd; }
    q = wave_sum(q);
    const float rstd = rsqrtf(q * (1.f / 512.f) + 1e-5f);
    const int row = row0 + r;
#pragma unroll
    for (int j = 0; j < 8; ++j) {
      int idx = lane + 64 * j;
      xn2b[(size_t)row * DMODEL + idx] = f2bf((v[j] - mu) * rstd * g2[idx] + be2[idx]);
    }
  }
}

// ---------------- bf16 MFMA GEMM:  C = A(M,K) @ B(N,K)^T  ----------------------------
// EPI=0: silu(acc+bias) -> bf16 Cb.   EPI=2: raw acc -> Cf + blockIdx.z*partStride.
template<int BM, int BN, int EPI>
__global__ __launch_bounds__(256) void k_mfma(
    const u16* __restrict__ A, const u16* __restrict__ B,
    const float* __restrict__ bias, float* __restrict__ Cf, u16* __restrict__ Cb,
    int K, int N, int kTiles, int partStride)
{
  constexpr int MF = BM / 32, NF = BN / 32;
  __shared__ __align__(16) u16 As[BM * 64];
  __shared__ __align__(16) u16 Bs[BN * 64];
  const int t = threadIdx.x;
  const int m0 = blockIdx.x * BM, n0 = blockIdx.y * BN;
  const int kBase = blockIdx.z * kTiles * 64;
  const int w = t >> 6, lane = t & 63;
  const int wm = w >> 1, wn = w & 1;
  const int lr = lane & 15, lk = lane >> 4;
  f32x4 acc[MF][NF] = {};

  for (int kt = 0; kt < kTiles; ++kt) {
    const int k0 = kBase + kt * 64;
#pragma unroll
    for (int i = 0; i < BM / 32; ++i) {
      int e = i * 2048 + t * 8;
      int row = e >> 6, col = e & 63;
      gload_lds16(A + (size_t)(m0 + row) * K + k0 + col, &As[e]);
    }
#pragma unroll
    for (int i = 0; i < BN / 32; ++i) {
      int e = i * 2048 + t * 8;
      int row = e >> 6, col = e & 63;
      gload_lds16(B + (size_t)(n0 + row) * K + k0 + col, &Bs[e]);
    }
    __syncthreads();
#pragma unroll
    for (int ks = 0; ks < 2; ++ks) {
      short8 af[MF], bf[NF];
#pragma unroll
      for (int mf = 0; mf < MF; ++mf)
        af[mf] = *(const short8*)&As[(wm * (BM / 2) + mf * 16 + lr) * 64 + ks * 32 + lk * 8];
#pragma unroll
      for (int nf = 0; nf < NF; ++nf)
        bf[nf] = *(const short8*)&Bs[(wn * (BN / 2) + nf * 16 + lr) * 64 + ks * 32 + lk * 8];
#pragma unroll
      for (int mf = 0; mf < MF; ++mf)
#pragma unroll
        for (int nf = 0; nf < NF; ++nf)
          acc[mf][nf] = __builtin_amdgcn_mfma_f32_16x16x32_bf16(af[mf], bf[nf], acc[mf][nf], 0, 0, 0);
    }
    __syncthreads();
  }

#pragma unroll
  for (int mf = 0; mf < MF; ++mf)
#pragma unroll
    for (int nf = 0; nf < NF; ++nf)
#pragma unroll
      for (int j = 0; j < 4; ++j) {
        int rrow = m0 + wm * (BM / 2) + mf * 16 + lk * 4 + j;
        int ccol = n0 + wn * (BN / 2) + nf * 16 + lr;
        if constexpr (EPI == 0) {
          float v = acc[mf][nf][j] + bias[ccol];
          v = v / (1.f + expf(-v));                       // silu
          Cb[(size_t)rrow * N + ccol] = f2bf(v);
        } else {
          Cf[(size_t)blockIdx.z * partStride + (size_t)rrow * N + ccol] = acc[mf][nf][j];
        }
      }
}

// ---------------- split-K reduce: out = p0+p1+p2+p3 + b2 + x2 ------------------------
// partStride4 is in float4 units!
__global__ __launch_bounds__(256) void k_red(
    const float* __restrict__ p, const float* __restrict__ b2,
    const float* __restrict__ x2, float* __restrict__ out, int n4, int partStride4)
{
  int i = blockIdx.x * 256 + threadIdx.x;
  if (i >= n4) return;
  const float4* p4 = (const float4*)p;
  float4 s = p4[i];
  float4 s1 = p4[i + partStride4];
  float4 s2 = p4[i + 2 * partStride4];
  float4 s3 = p4[i + 3 * partStride4];
  s.x += s1.x; s.y += s1.y; s.z += s1.z; s.w += s1.w;
  s.x += s2.x; s.y += s2.y; s.z += s2.z; s.w += s2.w;
  s.x += s3.x; s.y += s3.y; s.z += s3.z; s.w += s3.w;
  int col4 = i & 127;                       // N=512 -> 128 float4 per row
  float4 bb = ((const float4*)b2)[col4];
  float4 rr = ((const float4*)x2)[i];
  s.x += bb.x + rr.x; s.y += bb.y + rr.y; s.z += bb.z + rr.z; s.w += bb.w + rr.w;
  ((float4*)out)[i] = s;
}

// ---------------- launch -------------------------------------------------------------
extern "C" void kernel_launch(void* const* d_in, const int* in_sizes, int n_in,
                              void* d_out, int out_size, void* d_ws, size_t ws_size,
                              hipStream_t stream) {
  const float* x    = (const float*)d_in[0];
  const float* ln1g = (const float*)d_in[1];
  const float* ln1b = (const float*)d_in[2];
  const float* fcw  = (const float*)d_in[3];
  const float* fcb  = (const float*)d_in[4];
  const float* liw  = (const float*)d_in[5];
  const float* lib  = (const float*)d_in[6];
  const float* wa   = (const float*)d_in[7];
  const float* hidr = (const float*)d_in[8];
  const float* hidi = (const float*)d_in[9];
  const float* low  = (const float*)d_in[10];
  const float* lob  = (const float*)d_in[11];
  const float* ln2g = (const float*)d_in[12];
  const float* ln2b = (const float*)d_in[13];
  const float* w1   = (const float*)d_in[14];
  const float* b1   = (const float*)d_in[15];
  const float* w2   = (const float*)d_in[16];
  const float* b2   = (const float*)d_in[17];
  float* out = (float*)d_out;
  float* ws  = (float*)d_ws;

  const int R = 2 * LSEQ;                      // 1024 rows
  float* y_   = ws;
  float* u_   = y_  + (size_t)R * DT;
  float* ar_  = u_  + (size_t)R * DT;
  float* ai_  = ar_ + (size_t)R * DT;
  float* h_   = ai_ + (size_t)R * DT;
  float* x2_  = h_  + (size_t)R * DT;          // R*DMODEL floats
  float* part_ = x2_ + (size_t)R * DMODEL;     // 4 * R*DMODEL floats
  u16*  xn2b = (u16*)(part_ + (size_t)4 * R * DMODEL);
  u16*  h1b  = xn2b + (size_t)R * DMODEL;      // R*DFF
  u16*  w1b  = h1b  + (size_t)R * DFF;         // DFF*DMODEL
  u16*  w2b  = w1b  + (size_t)DFF * DMODEL;    // contiguous after w1b (k_cvt2 relies)

  k_cvt2<<<2048, 256, 0, stream>>>(w1, w2, w1b, (DFF * DMODEL) / 4);
  k_front<<<R / RBF, 256, 0, stream>>>(x, ln1g, ln1b, fcw, fcb, liw, lib, wa,
                                       y_, u_, ar_, ai_);
  k_scan2<<<128, 64, 0, stream>>>(u_, ar_, ai_, hidr, hidi, h_);
  k_mid<<<R / RBF, 256, 0, stream>>>(h_, y_, low, lob, x, ln2g, ln2b, x2_, xn2b);
  dim3 g1(R / 64, DFF / 64, 1);                // 512 blocks
  k_mfma<64, 64, 0><<<g1, 256, 0, stream>>>(xn2b, w1b, b1, nullptr, h1b,
                                            DMODEL, DFF, DMODEL / 64, 0);
  dim3 g2(R / 64, DMODEL / 64, 4);             // 512 blocks, split-K x4
  k_mfma<64, 64, 2><<<g2, 256, 0, stream>>>(h1b, w2b, nullptr, part_, nullptr,
                                            DFF, DMODEL, (DFF / 4) / 64, R * DMODEL);
  // partStride4 in float4 units: (R*DMODEL)/4  [round-3 bug: was R*DMODEL]
  k_red<<<(R * DMODEL / 4 + 255) / 256, 256, 0, stream>>>(part_, b2, x2_, out,
                                                          R * DMODEL / 4, R * DMODEL / 4);
}

// Round 7
// 62.470 us; speedup vs baseline: 5.0000x; 1.6216x over previous
//
#include <hip/hip_runtime.h>
#include <math.h>

#define LSEQ 512
#define DMODEL 512
#define DT 64
#define DFF 2048

typedef unsigned short u16;
typedef __attribute__((ext_vector_type(8))) short short8;
typedef __attribute__((ext_vector_type(4))) float f32x4;

__device__ __forceinline__ float wave_sum(float v) {
#pragma unroll
  for (int o = 32; o > 0; o >>= 1) v += __shfl_xor(v, o, 64);
  return v;
}

__device__ __forceinline__ u16 f2bf(float f) {
  unsigned int u = __float_as_uint(f);
  u += 0x7fffu + ((u >> 16) & 1u);
  return (u16)(u >> 16);
}
__device__ __forceinline__ float bf2f(u16 h) {
  return __uint_as_float(((unsigned int)h) << 16);
}
__device__ __forceinline__ void splitbf(float f, u16& h, u16& l) {
  h = f2bf(f);
  l = f2bf(f - bf2f(h));
}

__device__ __forceinline__ void gload_lds16(const void* g, void* l) {
  __builtin_amdgcn_global_load_lds(
      (const __attribute__((address_space(1))) unsigned int*)g,
      (__attribute__((address_space(3))) unsigned int*)l, 16, 0, 0);
}

// ---------------- weights fp32 -> bf16 (w1,w2 plain; small weights hi+lo) ------------
// float4-unit regions: w1[0,262144) w2[..524288) fcw[..532480) liw[..540672)
//                      wa[..542720) low[..550912)
__global__ __launch_bounds__(256) void k_cvtall(
    const float* __restrict__ w1, const float* __restrict__ w2,
    const float* __restrict__ fcw, const float* __restrict__ liw,
    const float* __restrict__ wa, const float* __restrict__ low,
    u16* __restrict__ w1b, u16* __restrict__ w2b,
    u16* __restrict__ fclh, u16* __restrict__ fcll,
    u16* __restrict__ wah, u16* __restrict__ wal,
    u16* __restrict__ lowh, u16* __restrict__ lowl)
{
  int i = blockIdx.x * 256 + threadIdx.x;
  if (i >= 550912) return;
  if (i < 524288) {                         // w1 / w2: plain bf16
    const float* s = (i < 262144) ? w1 : w2;
    u16* d = (i < 262144) ? w1b : w2b;
    int off = (i < 262144) ? i : i - 262144;
    float4 v = ((const float4*)s)[off];
    ushort4 o;
    o.x = f2bf(v.x); o.y = f2bf(v.y); o.z = f2bf(v.z); o.w = f2bf(v.w);
    ((ushort4*)d)[off] = o;
    return;
  }
  const float* s; int j; u16 *dh, *dl;
  if (i < 532480)      { s = fcw; j = i - 524288;        dh = fclh; dl = fcll; }
  else if (i < 540672) { s = liw; j = i - 532480 + 8192; dh = fclh; dl = fcll; }
  else if (i < 542720) { s = wa;  j = i - 540672;        dh = wah;  dl = wal;  }
  else                 { s = low; j = i - 542720;        dh = lowh; dl = lowl; }
  int soff = (i < 532480) ? i - 524288 :
             (i < 540672) ? i - 532480 :
             (i < 542720) ? i - 540672 : i - 542720;
  float4 v = ((const float4*)s)[soff];
  ushort4 oh, ol;
  splitbf(v.x, oh.x, ol.x); splitbf(v.y, oh.y, ol.y);
  splitbf(v.z, oh.z, ol.z); splitbf(v.w, oh.w, ol.w);
  ((ushort4*)dh)[j] = oh;
  ((ushort4*)dl)[j] = ol;
}

// ---------------- LayerNorm (row per wave). LO=1: write hi+lo bf16; else hi only -----
template<int LO>
__global__ __launch_bounds__(256) void k_ln(
    const float* __restrict__ in, const float* __restrict__ g,
    const float* __restrict__ be, u16* __restrict__ outh, u16* __restrict__ outl)
{
  const int lane = threadIdx.x & 63, wv = threadIdx.x >> 6;
  const int row = blockIdx.x * 4 + wv;
  const float* xr = in + (size_t)row * DMODEL;
  float v[8]; float s = 0.f;
#pragma unroll
  for (int j = 0; j < 8; ++j) { v[j] = xr[lane + 64 * j]; s += v[j]; }
  s = wave_sum(s);
  const float mu = s * (1.f / 512.f);
  float q = 0.f;
#pragma unroll
  for (int j = 0; j < 8; ++j) { float dd = v[j] - mu; q += dd * dd; }
  q = wave_sum(q);
  const float rstd = rsqrtf(q * (1.f / 512.f) + 1e-5f);
#pragma unroll
  for (int j = 0; j < 8; ++j) {
    int idx = lane + 64 * j;
    float o = (v[j] - mu) * rstd * g[idx] + be[idx];
    if constexpr (LO) {
      u16 h, l; splitbf(o, h, l);
      outh[(size_t)row * DMODEL + idx] = h;
      outl[(size_t)row * DMODEL + idx] = l;
    } else {
      outh[(size_t)row * DMODEL + idx] = f2bf(o);
    }
  }
}

// ---------------- fused fc + lin_in projection (wave-per-tile, bf16x3) ---------------
// grid (64,2), 256 thr. B rows 0-63 fc, 64-127 lin_in.
__global__ __launch_bounds__(256) void k_proj(
    const u16* __restrict__ xnh, const u16* __restrict__ xnl,
    const u16* __restrict__ fclh, const u16* __restrict__ fcll,
    const float* __restrict__ fcb, const float* __restrict__ lib,
    float* __restrict__ y_o, float* __restrict__ u_o,
    u16* __restrict__ ubh, u16* __restrict__ ubl)
{
  const int w = threadIdx.x >> 6, lane = threadIdx.x & 63;
  const int mt = blockIdx.x, nt = blockIdx.y * 4 + w;
  const int lr = lane & 15, lk = lane >> 4;
  const size_t aoff = (size_t)(mt * 16 + lr) * DMODEL + lk * 8;
  const size_t boff = (size_t)(nt * 16 + lr) * DMODEL + lk * 8;
  f32x4 acc = {};
#pragma unroll 4
  for (int k = 0; k < DMODEL; k += 32) {
    short8 ah = *(const short8*)(xnh + aoff + k);
    short8 al = *(const short8*)(xnl + aoff + k);
    short8 bh = *(const short8*)(fclh + boff + k);
    short8 bl = *(const short8*)(fcll + boff + k);
    acc = __builtin_amdgcn_mfma_f32_16x16x32_bf16(ah, bh, acc, 0, 0, 0);
    acc = __builtin_amdgcn_mfma_f32_16x16x32_bf16(ah, bl, acc, 0, 0, 0);
    acc = __builtin_amdgcn_mfma_f32_16x16x32_bf16(al, bh, acc, 0, 0, 0);
  }
  const int c = nt * 16 + lr;
#pragma unroll
  for (int j = 0; j < 4; ++j) {
    int row = mt * 16 + lk * 4 + j;
    float v = acc[j];
    if (c < DT) {
      v += fcb[c];
      y_o[row * DT + c] = v / (1.f + expf(-v));          // silu -> gate (fp32)
    } else {
      int d = c - DT;
      v += lib[d];
      u_o[row * DT + d] = v;                             // fp32 for scan
      u16 h, l; splitbf(v, h, l);
      ubh[row * DT + d] = h;                             // hi/lo for au GEMM
      ubl[row * DT + d] = l;
    }
  }
}

// ---------------- au = u @ wa^T (bf16x3), then a-map ---------------------------------
// grid (64,2). (re,im) = adjacent cols -> exchange via shfl_xor(lane,1).
__global__ __launch_bounds__(256) void k_au(
    const u16* __restrict__ ubh, const u16* __restrict__ ubl,
    const u16* __restrict__ wah, const u16* __restrict__ wal,
    float* __restrict__ ar_o, float* __restrict__ ai_o)
{
  const int w = threadIdx.x >> 6, lane = threadIdx.x & 63;
  const int mt = blockIdx.x, nt = blockIdx.y * 4 + w;
  const int lr = lane & 15, lk = lane >> 4;
  const size_t aoff = (size_t)(mt * 16 + lr) * DT + lk * 8;
  const size_t boff = (size_t)(nt * 16 + lr) * DT + lk * 8;
  f32x4 acc = {};
#pragma unroll
  for (int k = 0; k < DT; k += 32) {
    short8 ah = *(const short8*)(ubh + aoff + k);
    short8 al = *(const short8*)(ubl + aoff + k);
    short8 bh = *(const short8*)(wah + boff + k);
    short8 bl = *(const short8*)(wal + boff + k);
    acc = __builtin_amdgcn_mfma_f32_16x16x32_bf16(ah, bh, acc, 0, 0, 0);
    acc = __builtin_amdgcn_mfma_f32_16x16x32_bf16(ah, bl, acc, 0, 0, 0);
    acc = __builtin_amdgcn_mfma_f32_16x16x32_bf16(al, bh, acc, 0, 0, 0);
  }
  const int c = nt * 16 + lr;
#pragma unroll
  for (int j = 0; j < 4; ++j) {
    float v = acc[j];
    float p = __shfl_xor(v, 1, 64);
    float re = (lane & 1) ? p : v;
    float im = (lane & 1) ? v : p;
    float asq = re * re + im * im;
    float sc = rsqrtf(asq) * expf(-asq);
    int row = mt * 16 + lk * 4 + j;
    int d = c >> 1;
    if (lane & 1) ai_o[row * DT + d] = im * sc;
    else          ar_o[row * DT + d] = re * sc;
  }
}

// ---------------- parallel backward affine scan (unchanged) --------------------------
__global__ __launch_bounds__(64) void k_scan2(
    const float* __restrict__ u, const float* __restrict__ ar, const float* __restrict__ ai,
    const float* __restrict__ hr, const float* __restrict__ hi, float* __restrict__ h_o)
{
  const int blk = blockIdx.x;             // 0..127
  const int b = blk >> 6, d = blk & 63;
  const int lane = threadIdx.x;           // 0..63
  const size_t base = (size_t)b * LSEQ * DT + d;
  const int i0 = lane * 8;

  float a_r[8], a_i[8], b_r[8], b_i[8];
#pragma unroll
  for (int e = 0; e < 8; ++e) {
    int i = i0 + e;
    a_r[e] = ar[base + (size_t)i * DT];
    a_i[e] = ai[base + (size_t)i * DT];
    if (i >= 2)      { b_r[e] = u[base + (size_t)(i - 2) * DT]; b_i[e] = 0.f; }
    else if (i == 1) { b_r[e] = hr[d]; b_i[e] = hi[d]; }
    else             { b_r[e] = 0.f;   b_i[e] = 0.f; }
  }

  float Ar = 1.f, Ai = 0.f, Br = 0.f, Bi = 0.f;
#pragma unroll
  for (int e = 0; e < 8; ++e) {
    float nBr = fmaf(Ar, b_r[e], fmaf(-Ai, b_i[e], Br));
    float nBi = fmaf(Ar, b_i[e], fmaf( Ai, b_r[e], Bi));
    float nAr = Ar * a_r[e] - Ai * a_i[e];
    float nAi = Ar * a_i[e] + Ai * a_r[e];
    Ar = nAr; Ai = nAi; Br = nBr; Bi = nBi;
  }

#pragma unroll
  for (int dlt = 1; dlt < 64; dlt <<= 1) {
    float Ar2 = __shfl_down(Ar, dlt, 64);
    float Ai2 = __shfl_down(Ai, dlt, 64);
    float Br2 = __shfl_down(Br, dlt, 64);
    float Bi2 = __shfl_down(Bi, dlt, 64);
    if (lane + dlt < 64) {
      float nAr = Ar * Ar2 - Ai * Ai2;
      float nAi = Ar * Ai2 + Ai * Ar2;
      float nBr = fmaf(Ar, Br2, fmaf(-Ai, Bi2, Br));
      float nBi = fmaf(Ar, Bi2, fmaf( Ai, Br2, Bi));
      Ar = nAr; Ai = nAi; Br = nBr; Bi = nBi;
    }
  }

  float A1r = __shfl_down(Ar, 1, 64), A1i = __shfl_down(Ai, 1, 64);
  float B1r = __shfl_down(Br, 1, 64), B1i = __shfl_down(Bi, 1, 64);
  if (lane == 63) { A1r = 1.f; A1i = 0.f; B1r = 0.f; B1i = 0.f; }
  const float r512 = u[base + (size_t)(LSEQ - 2) * DT];
  float rr = fmaf(A1r, r512, B1r);
  float ri = fmaf(A1i, r512, B1i);

  const float uL = u[base + (size_t)(LSEQ - 1) * DT];
#pragma unroll
  for (int e = 7; e >= 0; --e) {
    int i = i0 + e;
    float nr = fmaf(a_r[e], rr, fmaf(-a_i[e], ri, b_r[e]));
    float ni = fmaf(a_r[e], ri, fmaf( a_i[e], rr, b_i[e]));
    rr = nr; ri = ni;
    float outv = rr;
    if (i == LSEQ - 1) outv += uL;
    h_o[base + (size_t)i * DT] = outv;
  }
}

// ---------------- mid: x2 = (h*y) @ low^T + lob + x  (wave-per-tile, bf16x3) ---------
// grid (64, 8). A-fragment (h*y) split hi/lo in-register.
__global__ __launch_bounds__(256) void k_mid2(
    const float* __restrict__ h, const float* __restrict__ y,
    const u16* __restrict__ lowh, const u16* __restrict__ lowl,
    const float* __restrict__ lob, const float* __restrict__ x,
    float* __restrict__ x2_o)
{
  const int w = threadIdx.x >> 6, lane = threadIdx.x & 63;
  const int mt = blockIdx.x, nt = blockIdx.y * 4 + w;
  const int lr = lane & 15, lk = lane >> 4;
  const int arow = mt * 16 + lr;
  const float* hp = h + (size_t)arow * DT + lk * 8;
  const float* yp = y + (size_t)arow * DT + lk * 8;
  const size_t boff = (size_t)(nt * 16 + lr) * DT + lk * 8;
  f32x4 acc = {};
#pragma unroll
  for (int ks = 0; ks < 2; ++ks) {
    float4 h0 = *(const float4*)(hp + ks * 32);
    float4 h1 = *(const float4*)(hp + ks * 32 + 4);
    float4 y0 = *(const float4*)(yp + ks * 32);
    float4 y1 = *(const float4*)(yp + ks * 32 + 4);
    float pv[8] = {h0.x * y0.x, h0.y * y0.y, h0.z * y0.z, h0.w * y0.w,
                   h1.x * y1.x, h1.y * y1.y, h1.z * y1.z, h1.w * y1.w};
    short8 ah, al;
#pragma unroll
    for (int e = 0; e < 8; ++e) {
      u16 hh, ll; splitbf(pv[e], hh, ll);
      ah[e] = (short)hh; al[e] = (short)ll;
    }
    short8 bh = *(const short8*)(lowh + boff + ks * 32);
    short8 bl = *(const short8*)(lowl + boff + ks * 32);
    acc = __builtin_amdgcn_mfma_f32_16x16x32_bf16(ah, bh, acc, 0, 0, 0);
    acc = __builtin_amdgcn_mfma_f32_16x16x32_bf16(ah, bl, acc, 0, 0, 0);
    acc = __builtin_amdgcn_mfma_f32_16x16x32_bf16(al, bh, acc, 0, 0, 0);
  }
  const int c = nt * 16 + lr;
#pragma unroll
  for (int j = 0; j < 4; ++j) {
    int row = mt * 16 + lk * 4 + j;
    x2_o[(size_t)row * DMODEL + c] = acc[j] + lob[c] + x[(size_t)row * DMODEL + c];
  }
}

// ---------------- bf16 MFMA GEMM (FFN), LDS-staged ------------------------------------
// EPI=0: silu(acc+bias) -> bf16 Cb.   EPI=2: raw acc -> Cf + blockIdx.z*partStride.
template<int BM, int BN, int EPI>
__global__ __launch_bounds__(256) void k_mfma(
    const u16* __restrict__ A, const u16* __restrict__ B,
    const float* __restrict__ bias, float* __restrict__ Cf, u16* __restrict__ Cb,
    int K, int N, int kTiles, int partStride)
{
  constexpr int MF = BM / 32, NF = BN / 32;
  __shared__ __align__(16) u16 As[BM * 64];
  __shared__ __align__(16) u16 Bs[BN * 64];
  const int t = threadIdx.x;
  const int m0 = blockIdx.x * BM, n0 = blockIdx.y * BN;
  const int kBase = blockIdx.z * kTiles * 64;
  const int w = t >> 6, lane = t & 63;
  const int wm = w >> 1, wn = w & 1;
  const int lr = lane & 15, lk = lane >> 4;
  f32x4 acc[MF][NF] = {};

  for (int kt = 0; kt < kTiles; ++kt) {
    const int k0 = kBase + kt * 64;
#pragma unroll
    for (int i = 0; i < BM / 32; ++i) {
      int e = i * 2048 + t * 8;
      int row = e >> 6, col = e & 63;
      gload_lds16(A + (size_t)(m0 + row) * K + k0 + col, &As[e]);
    }
#pragma unroll
    for (int i = 0; i < BN / 32; ++i) {
      int e = i * 2048 + t * 8;
      int row = e >> 6, col = e & 63;
      gload_lds16(B + (size_t)(n0 + row) * K + k0 + col, &Bs[e]);
    }
    __syncthreads();
#pragma unroll
    for (int ks = 0; ks < 2; ++ks) {
      short8 af[MF], bf[NF];
#pragma unroll
      for (int mf = 0; mf < MF; ++mf)
        af[mf] = *(const short8*)&As[(wm * (BM / 2) + mf * 16 + lr) * 64 + ks * 32 + lk * 8];
#pragma unroll
      for (int nf = 0; nf < NF; ++nf)
        bf[nf] = *(const short8*)&Bs[(wn * (BN / 2) + nf * 16 + lr) * 64 + ks * 32 + lk * 8];
#pragma unroll
      for (int mf = 0; mf < MF; ++mf)
#pragma unroll
        for (int nf = 0; nf < NF; ++nf)
          acc[mf][nf] = __builtin_amdgcn_mfma_f32_16x16x32_bf16(af[mf], bf[nf], acc[mf][nf], 0, 0, 0);
    }
    __syncthreads();
  }

#pragma unroll
  for (int mf = 0; mf < MF; ++mf)
#pragma unroll
    for (int nf = 0; nf < NF; ++nf)
#pragma unroll
      for (int j = 0; j < 4; ++j) {
        int rrow = m0 + wm * (BM / 2) + mf * 16 + lk * 4 + j;
        int ccol = n0 + wn * (BN / 2) + nf * 16 + lr;
        if constexpr (EPI == 0) {
          float v = acc[mf][nf][j] + bias[ccol];
          v = v / (1.f + expf(-v));                       // silu
          Cb[(size_t)rrow * N + ccol] = f2bf(v);
        } else {
          Cf[(size_t)blockIdx.z * partStride + (size_t)rrow * N + ccol] = acc[mf][nf][j];
        }
      }
}

// ---------------- split-K reduce: out = p0+p1+p2+p3 + b2 + x2 ------------------------
// partStride4 is in float4 units!
__global__ __launch_bounds__(256) void k_red(
    const float* __restrict__ p, const float* __restrict__ b2,
    const float* __restrict__ x2, float* __restrict__ out, int n4, int partStride4)
{
  int i = blockIdx.x * 256 + threadIdx.x;
  if (i >= n4) return;
  const float4* p4 = (const float4*)p;
  float4 s = p4[i];
  float4 s1 = p4[i + partStride4];
  float4 s2 = p4[i + 2 * partStride4];
  float4 s3 = p4[i + 3 * partStride4];
  s.x += s1.x; s.y += s1.y; s.z += s1.z; s.w += s1.w;
  s.x += s2.x; s.y += s2.y; s.z += s2.z; s.w += s2.w;
  s.x += s3.x; s.y += s3.y; s.z += s3.z; s.w += s3.w;
  int col4 = i & 127;                       // N=512 -> 128 float4 per row
  float4 bb = ((const float4*)b2)[col4];
  float4 rr = ((const float4*)x2)[i];
  s.x += bb.x + rr.x; s.y += bb.y + rr.y; s.z += bb.z + rr.z; s.w += bb.w + rr.w;
  ((float4*)out)[i] = s;
}

// ---------------- launch -------------------------------------------------------------
extern "C" void kernel_launch(void* const* d_in, const int* in_sizes, int n_in,
                              void* d_out, int out_size, void* d_ws, size_t ws_size,
                              hipStream_t stream) {
  const float* x    = (const float*)d_in[0];
  const float* ln1g = (const float*)d_in[1];
  const float* ln1b = (const float*)d_in[2];
  const float* fcw  = (const float*)d_in[3];
  const float* fcb  = (const float*)d_in[4];
  const float* liw  = (const float*)d_in[5];
  const float* lib  = (const float*)d_in[6];
  const float* wa   = (const float*)d_in[7];
  const float* hidr = (const float*)d_in[8];
  const float* hidi = (const float*)d_in[9];
  const float* low  = (const float*)d_in[10];
  const float* lob  = (const float*)d_in[11];
  const float* ln2g = (const float*)d_in[12];
  const float* ln2b = (const float*)d_in[13];
  const float* w1   = (const float*)d_in[14];
  const float* b1   = (const float*)d_in[15];
  const float* w2   = (const float*)d_in[16];
  const float* b2   = (const float*)d_in[17];
  float* out = (float*)d_out;
  float* ws  = (float*)d_ws;

  const int R = 2 * LSEQ;                      // 1024 rows
  float* y_    = ws;                           // 65536
  float* u_    = y_   + 65536;
  float* ar_   = u_   + 65536;
  float* ai_   = ar_  + 65536;
  float* h_    = ai_  + 65536;
  float* x2_   = h_   + 65536;                 // 524288
  float* part_ = x2_  + 524288;                // 2097152
  u16* p = (u16*)(part_ + 2097152);
  u16* xnh  = p;            p += 524288;
  u16* xnl  = p;            p += 524288;
  u16* xn2b = p;            p += 524288;
  u16* ubh  = p;            p += 65536;
  u16* ubl  = p;            p += 65536;
  u16* h1b  = p;            p += 2097152;
  u16* w1b  = p;            p += 1048576;
  u16* w2b  = p;            p += 1048576;
  u16* fclh = p;            p += 65536;
  u16* fcll = p;            p += 65536;
  u16* wah  = p;            p += 8192;
  u16* wal  = p;            p += 8192;
  u16* lowh = p;            p += 32768;
  u16* lowl = p;            p += 32768;

  k_cvtall<<<2152, 256, 0, stream>>>(w1, w2, fcw, liw, wa, low,
                                     w1b, w2b, fclh, fcll, wah, wal, lowh, lowl);
  k_ln<1><<<256, 256, 0, stream>>>(x, ln1g, ln1b, xnh, xnl);
  k_proj<<<dim3(64, 2), 256, 0, stream>>>(xnh, xnl, fclh, fcll, fcb, lib,
                                          y_, u_, ubh, ubl);
  k_au<<<dim3(64, 2), 256, 0, stream>>>(ubh, ubl, wah, wal, ar_, ai_);
  k_scan2<<<128, 64, 0, stream>>>(u_, ar_, ai_, hidr, hidi, h_);
  k_mid2<<<dim3(64, 8), 256, 0, stream>>>(h_, y_, lowh, lowl, lob, x, x2_);
  k_ln<0><<<256, 256, 0, stream>>>(x2_, ln2g, ln2b, xn2b, nullptr);
  dim3 g1(R / 64, DFF / 64);                   // (16,32) = 512 blocks
  k_mfma<64, 64, 0><<<g1, 256, 0, stream>>>(xn2b, w1b, b1, nullptr, h1b,
                                            DMODEL, DFF, DMODEL / 64, 0);
  dim3 g2(R / 64, DMODEL / 64, 4);             // 512 blocks, split-K x4
  k_mfma<64, 64, 2><<<g2, 256, 0, stream>>>(h1b, w2b, nullptr, part_, nullptr,
                                            DFF, DMODEL, (DFF / 4) / 64, R * DMODEL);
  k_red<<<(R * DMODEL / 4 + 255) / 256, 256, 0, stream>>>(part_, b2, x2_, out,
                                                          R * DMODEL / 4, R * DMODEL / 4);
}